// Round 17
// baseline (129.203 us; speedup 1.0000x reference)
//
#include <hip/hip_runtime.h>
#include <stdint.h>

typedef _Float16  f16;
typedef f16       f16x2  __attribute__((ext_vector_type(2)));
typedef f16       f16x8  __attribute__((ext_vector_type(8)));
typedef float     f32x16v __attribute__((ext_vector_type(16)));
typedef float     f32x4v  __attribute__((ext_vector_type(4)));
typedef uint32_t  u32x4v  __attribute__((ext_vector_type(4)));
typedef unsigned short u16;

__device__ __forceinline__ f32x16v mfma16h(u32x4v a, u32x4v b, f32x16v c) {
  return __builtin_amdgcn_mfma_f32_32x32x16_f16(
      __builtin_bit_cast(f16x8, a), __builtin_bit_cast(f16x8, b), c, 0, 0, 0);
}

// prep: W f32 [65][i=64][k=64] -> fragment-major f16 arrays, PADDED to 68 j
// (j=65..67 zero => zero K-contribution; keeps all 17 chunks uniform).
// elem idx = jj*4096 + (ct*4+s)*512 + l*8 + e  (l = lane)
//   w1h: W[jj][ i=s*16+(l>>5)*8+e ][ k=ct*32+(l&31) ]
//   w2h: W[jj][ e_row=ct*32+(l&31) ][ k=s*16+(l>>5)*8+e ]
__global__ __launch_bounds__(256) void prep_w(const float* __restrict__ W,
                                              u16* __restrict__ w1h,
                                              u16* __restrict__ w2h) {
  __shared__ float Wl[4096];
  const int jj = blockIdx.x;          // 0..67
  const int t  = threadIdx.x;
  if (jj >= 65) {
    for (int idx = t; idx < 4096; idx += 256) {
      w1h[jj * 4096 + idx] = 0;
      w2h[jj * 4096 + idx] = 0;
    }
    return;
  }
  for (int idx = t; idx < 4096; idx += 256) Wl[idx] = W[jj * 4096 + idx];
  __syncthreads();
  for (int pq = t; pq < 512; pq += 256) {
    const int c2 = pq >> 6, l = pq & 63;
    const int ct = c2 >> 2, s = c2 & 3;
    const int rowA = ct * 32 + (l & 31);
    const int k0   = s * 16 + (l >> 5) * 8;
    u16 v1[8], v2[8];
    #pragma unroll
    for (int e = 0; e < 8; ++e) {
      v2[e] = __builtin_bit_cast(u16, (f16)Wl[rowA * 64 + k0 + e]);
      v1[e] = __builtin_bit_cast(u16, (f16)Wl[(k0 + e) * 64 + rowA]);
    }
    u32x4v pk1, pk2;
    #pragma unroll
    for (int q = 0; q < 4; ++q) {
      pk1[q] = (uint32_t)v1[2*q] | ((uint32_t)v1[2*q+1] << 16);
      pk2[q] = (uint32_t)v2[2*q] | ((uint32_t)v2[2*q+1] << 16);
    }
    *reinterpret_cast<u32x4v*>(w1h + jj * 4096 + pq * 8) = pk1;
    *reinterpret_cast<u32x4v*>(w2h + jj * 4096 + pq * 8) = pk2;
  }
}

// main: grid 256 (1 block/CU), 512 thr (8 waves = ct2 x sq4), BB=128.
// B-fragments DIRECT to VGPRs (role-split: zero duplication; compiler emits
// precise per-use vmcnt — no drains). RAW s_barrier pacing per 4-j chunk
// keeps all waves phase-locked (pure rendezvous; no LDS hazard in K-loop).
// 3-bank register pipeline, 2 chunks ahead, fully static indexing.
__global__ __launch_bounds__(512) void rquad_main(
    const float* __restrict__ x, const float* __restrict__ g,
    const u16* __restrict__ w1h, const u16* __restrict__ w2h,
    float* __restrict__ out) {
  __shared__ __align__(16) float    vl[128 * 68];   // 34.8 KB combine buffer
  __shared__ __align__(16) uint32_t x1p[68 * 64];   // 17.4 KB packed x1 pairs

  const int t    = threadIdx.x;
  const int lane = t & 63;
  const int wv   = t >> 6;
  const int ct   = wv >> 2;        // output-col half
  const int sq   = wv & 3;         // K-quarter
  const int bl   = lane & 31;
  const int half = lane >> 5;
  const long base = (long)blockIdx.x * 128;

  // prologue: x -> vl (coalesced) -> x1p[j][q] = (f16 x[q][j], f16 x[64+q][j])
  for (int q = t; q < 2048; q += 512) {
    const int row = q >> 4, c4 = (q & 15) * 4;
    *reinterpret_cast<f32x4v*>(&vl[row * 68 + c4]) =
        *reinterpret_cast<const f32x4v*>(&x[(base + row) * 64 + c4]);
  }
  __syncthreads();
  for (int idx = t; idx < 68 * 64; idx += 512) {
    const int j = idx >> 6, q = idx & 63;
    uint32_t val;
    if (j == 64)     val = 0x3C003C00u;   // bias 1.0,1.0
    else if (j > 64) val = 0u;            // pad (W zero there)
    else {
      f16 a = (f16)vl[q * 68 + j];
      f16 b = (f16)vl[(64 + q) * 68 + j];
      val = (uint32_t)__builtin_bit_cast(u16, a) |
            ((uint32_t)__builtin_bit_cast(u16, b) << 16);
    }
    x1p[idx] = val;
  }
  // z init from g: K-slice i = sq*16 + half*8 + 0..7, per sample tile
  f16x2 z[4][4];
  #pragma unroll
  for (int tt = 0; tt < 4; ++tt) {
    const float* gp = g + (base + tt * 32 + bl) * 64 + sq * 16 + half * 8;
    f32x4v a = *reinterpret_cast<const f32x4v*>(gp);
    f32x4v b = *reinterpret_cast<const f32x4v*>(gp + 4);
    z[tt][0] = f16x2{(f16)a[0], (f16)a[1]};
    z[tt][1] = f16x2{(f16)a[2], (f16)a[3]};
    z[tt][2] = f16x2{(f16)b[0], (f16)b[1]};
    z[tt][3] = f16x2{(f16)b[2], (f16)b[3]};
  }
  __syncthreads();   // x1p ready

  f32x16v acc[4];

  auto compute_1j = [&](int jglob, u32x4v B) {
    const uint32_t xw0 = x1p[jglob * 64 + bl];        // tiles 0(lo), 2(hi)
    const uint32_t xw1 = x1p[jglob * 64 + 32 + bl];   // tiles 1(lo), 3(hi)
    const f16x2 xp0 = __builtin_bit_cast(f16x2, xw0);
    const f16x2 xp1 = __builtin_bit_cast(f16x2, xw1);
    const f16x2 xb0 = f16x2{xp0[0], xp0[0]};
    const f16x2 xb1 = f16x2{xp1[0], xp1[0]};
    const f16x2 xb2 = f16x2{xp0[1], xp0[1]};
    const f16x2 xb3 = f16x2{xp1[1], xp1[1]};
    u32x4v a0, a1, a2, a3;
    #pragma unroll
    for (int q = 0; q < 4; ++q) {
      a0[q] = __builtin_bit_cast(uint32_t, f16x2(xb0 * z[0][q]));
      a1[q] = __builtin_bit_cast(uint32_t, f16x2(xb1 * z[1][q]));
      a2[q] = __builtin_bit_cast(uint32_t, f16x2(xb2 * z[2][q]));
      a3[q] = __builtin_bit_cast(uint32_t, f16x2(xb3 * z[3][q]));
    }
    acc[0] = mfma16h(a0, B, acc[0]);
    acc[1] = mfma16h(a1, B, acc[1]);
    acc[2] = mfma16h(a2, B, acc[2]);
    acc[3] = mfma16h(a3, B, acc[3]);
  };

  auto run_pass = [&](const u16* __restrict__ Wsrc) {
    #pragma unroll
    for (int tt = 0; tt < 4; ++tt)
      #pragma unroll
      for (int r = 0; r < 16; ++r) acc[tt][r] = 0.0f;
    const u16* wr = Wsrc + (ct * 4 + sq) * 512 + lane * 8;
    u32x4v b0[4], b1[4], b2[4];
    auto LD = [&](int c, u32x4v (&bk)[4]) {
      #pragma unroll
      for (int jl = 0; jl < 4; ++jl)
        bk[jl] = *reinterpret_cast<const u32x4v*>(wr + (size_t)(c * 4 + jl) * 4096);
    };
    auto CP = [&](int c, u32x4v (&bk)[4]) {
      #pragma unroll
      for (int jl = 0; jl < 4; ++jl) compute_1j(c * 4 + jl, bk[jl]);
    };
    LD(0, b0); LD(1, b1);
    for (int cc = 0; cc < 15; cc += 3) {   // cc = 0,3,6,9,12
      LD(cc + 2, b2); CP(cc + 0, b0); __builtin_amdgcn_s_barrier();
      LD(cc + 3, b0); CP(cc + 1, b1); __builtin_amdgcn_s_barrier();
      LD(cc + 4, b1); CP(cc + 2, b2); __builtin_amdgcn_s_barrier();
    }
    CP(15, b0); __builtin_amdgcn_s_barrier();
    CP(16, b1);
  };

  auto combine = [&]() {
    __syncthreads();
    for (int idx = t; idx < 128 * 68; idx += 512) vl[idx] = 0.0f;
    __syncthreads();
    #pragma unroll
    for (int tt = 0; tt < 4; ++tt)
      #pragma unroll
      for (int r = 0; r < 16; ++r) {
        const int rr = (r & 3) + 8 * (r >> 2) + 4 * half;
        atomicAdd(&vl[(tt * 32 + rr) * 68 + ct * 32 + bl], acc[tt][r]);
      }
    __syncthreads();
  };

  // ---------------- pass 1: v[b,k] ----------------
  run_pass(w1h);
  combine();
  // z <- v (f32 -> f16), K-slice k = sq*16 + half*8 + 0..7
  #pragma unroll
  for (int tt = 0; tt < 4; ++tt) {
    const float* vp = &vl[(tt * 32 + bl) * 68 + sq * 16 + half * 8];
    f32x4v a = *reinterpret_cast<const f32x4v*>(vp);
    f32x4v b = *reinterpret_cast<const f32x4v*>(vp + 4);
    z[tt][0] = f16x2{(f16)a[0], (f16)a[1]};
    z[tt][1] = f16x2{(f16)a[2], (f16)a[3]};
    z[tt][2] = f16x2{(f16)b[0], (f16)b[1]};
    z[tt][3] = f16x2{(f16)b[2], (f16)b[3]};
  }
  __syncthreads();

  // ---------------- pass 2: out[b,e] ----------------
  run_pass(w2h);
  combine();
  for (int q = t; q < 2048; q += 512) {
    const int row = q >> 4, c4 = (q & 15) * 4;
    f32x4v v4 = *reinterpret_cast<const f32x4v*>(&vl[row * 68 + c4]);
    f32x4v o;
    o[0] = v4[0] * 0.125f; o[1] = v4[1] * 0.125f;
    o[2] = v4[2] * 0.125f; o[3] = v4[3] * 0.125f;
    *reinterpret_cast<f32x4v*>(&out[(base + row) * 64 + c4]) = o;
  }
}

extern "C" void kernel_launch(void* const* d_in, const int* in_sizes, int n_in,
                              void* d_out, int out_size, void* d_ws, size_t ws_size,
                              hipStream_t stream) {
  const float* x = (const float*)d_in[0];
  const float* g = (const float*)d_in[1];
  const float* W = (const float*)d_in[2];
  float* o = (float*)d_out;
  u16* w1h = (u16*)d_ws;                    // 68*4096 f16 = 557 KiB (padded)
  u16* w2h = w1h + 68 * 4096;               // another 557 KiB
  hipLaunchKernelGGL(prep_w, dim3(68), dim3(256), 0, stream, W, w1h, w2h);
  hipLaunchKernelGGL(rquad_main, dim3(256), dim3(512), 0, stream, x, g, w1h, w2h, o);
}